// Round 11
// baseline (390.744 us; speedup 1.0000x reference)
//
#include <hip/hip_runtime.h>

// GAT layer: N=100000 nodes, E=1600000 edges, 4 heads, D_in=128, D_out=32.
// Dtypes (settled): floats f32 (bf16-valued: lo-split == 0 bitwise), edge_index
// int64 (ballot-detected), output f32. Hw stored bf16.
// Round-17: k_hw REPLACED, not edited. r12/r13/r16 all failed on structural
// edits to the staged-LDS/barrier k_hw body (mechanism never found); r15
// measured it at 47us / 25% occupancy / everything idle. New design removes
// the failure surface entirely:
//  - k_wprep (1 blk, old k_prep pattern, passed rounds 1-9): W -> bf16 global
//    (32KB, L2-hot), v=W^T A in f32 -> split-bf16 S arrays (rows 8..15 zero),
//    cnt[] zeroed.
//  - k_hw2: 512 thr = 8 independent waves, grid 782 (the PASSING 128-node
//    block geometry; wave w owns tile w). ZERO LDS, ZERO barriers. B-fragments
//    read directly from L2-hot Wb/Sg arrays. Same MFMA sequence/order ->
//    bit-identical output. hb halves sequential to keep VGPR <= 64.
//    Occupancy 12 -> ~24 waves/CU.
// k_scatA / k_locs / k_aggr: byte-identical to round-14 (248.1us, 0.03125).
// Pipeline: k_wprep -> k_hw2 -> k_scatA -> k_locs -> k_aggr.

#define CHUNK 4096
#define CAP 8192

typedef __attribute__((ext_vector_type(8))) short short8_t;
typedef __attribute__((ext_vector_type(4))) float float4v;
typedef __attribute__((ext_vector_type(2))) float float2v;

static __device__ inline float bf2f(unsigned short u) {
    return __uint_as_float(((unsigned int)u) << 16);
}
static __device__ inline unsigned short f2bf(float f) {
    unsigned int u = __float_as_uint(f);
    return (unsigned short)((u + 0x7fffu + ((u >> 16) & 1u)) >> 16);
}
static __device__ inline void splitf(float v, unsigned short& h, unsigned short& l) {
    unsigned short hb = f2bf(v);
    h = hb;
    l = f2bf(v - bf2f(hb));  // residual exact in f32
}

// ---------------- 256-thread block exclusive scan helper
__device__ inline int block_excl_scan(int v) {
    __shared__ int wsum[8];
    int lane = threadIdx.x & 63, w = threadIdx.x >> 6;
    int inc = v;
    for (int d = 1; d < 64; d <<= 1) {
        int t = __shfl_up(inc, d, 64);
        if (lane >= d) inc += t;
    }
    if (lane == 63) wsum[w] = inc;
    __syncthreads();
    int base = 0;
    for (int i = 0; i < w; ++i) base += wsum[i];
    __syncthreads();
    return base + inc - v;
}

// ---------------- k_wprep: 1 block. W->bf16 global; S = split-bf16 of W^T A
// (rows 0..3 = v_src heads, 4..7 = v_tgt heads, 8..15 = zero); cnt[] zeroed.
__global__ __launch_bounds__(256) void k_wprep(const float* __restrict__ Wf,
                                               const float* __restrict__ Asrc,
                                               const float* __restrict__ Atgt,
                                               unsigned short* __restrict__ Wb,
                                               unsigned short* __restrict__ Sgh,
                                               unsigned short* __restrict__ Sgl,
                                               int* __restrict__ cnt, int NB) {
    __shared__ float As[128], At[128];
    const int tid = threadIdx.x;
    for (int i = tid; i < NB; i += 256) cnt[i] = 0;
    if (tid < 128) {
        As[tid] = Asrc[tid];
        At[tid] = Atgt[tid];
    }
    __syncthreads();
    // W conversion: 16384 f32 -> bf16, vectorized 4-at-a-time
    for (int i = tid; i < 4096; i += 256) {
        float4v v = ((const float4v*)Wf)[i];
        ushort4 h4;
        h4.x = f2bf(v[0]);
        h4.y = f2bf(v[1]);
        h4.z = f2bf(v[2]);
        h4.w = f2bf(v[3]);
        *(ushort4*)&Wb[i * 4] = h4;
    }
    // S rows: v[h][k] = sum_o W[h*32+o][k] * A[h*32+o] (f32, o ascending — same
    // sequence as the staged version), then splitf.
    for (int p = tid; p < 2048; p += 256) {
        int r = p >> 7, k = p & 127;
        float v = 0.f;
        if (r < 8) {
            int hh = r & 3;
            const float* Ap = (r < 4) ? As : At;
            for (int o = 0; o < 32; ++o)
                v += Wf[((size_t)(hh * 32 + o)) * 128 + k] * Ap[hh * 32 + o];
        }
        unsigned short hh_, ll_;
        splitf(v, hh_, ll_);
        Sgh[p] = hh_;
        Sgl[p] = ll_;
    }
}

// ---------------- k_hw2: barrier-free, LDS-free GEMM + scores.
// 512 thr = 8 waves; wave w owns nodes [blk*128 + w*16, +16). B-fragments from
// L2-hot Wb/Sg. Same MFMA accumulation order as the staged version.
__global__ __launch_bounds__(512) void k_hw2(const float* __restrict__ Hf,
                                             const unsigned short* __restrict__ Wb,
                                             const unsigned short* __restrict__ Sgh,
                                             const unsigned short* __restrict__ Sgl,
                                             unsigned short* __restrict__ Hwb,
                                             float* __restrict__ s_src,
                                             float* __restrict__ s_tgt, int nnodes) {
    int wave = threadIdx.x >> 6;  // 0..7
    int lane = threadIdx.x & 63;
    int mrow = lane & 15;
    int quad = lane >> 4;
    int nbase = blockIdx.x * 128 + wave * 16;
    if (nbase >= nnodes) return;  // wave-uniform; no barriers anywhere
    int anode = nbase + mrow;
    int nclamp = anode < nnodes ? anode : nnodes - 1;
    const float* Hp = Hf + (size_t)nclamp * 128 + quad * 8;

    // H fragments (A-operand), identical f2bf per element
    short8_t ah[4];
    for (int kc = 0; kc < 4; ++kc) {
        float4v va = *(const float4v*)(Hp + kc * 32);
        float4v vb = *(const float4v*)(Hp + kc * 32 + 4);
        ah[kc][0] = (short)f2bf(va[0]);
        ah[kc][1] = (short)f2bf(va[1]);
        ah[kc][2] = (short)f2bf(va[2]);
        ah[kc][3] = (short)f2bf(va[3]);
        ah[kc][4] = (short)f2bf(vb[0]);
        ah[kc][5] = (short)f2bf(vb[1]);
        ah[kc][6] = (short)f2bf(vb[2]);
        ah[kc][7] = (short)f2bf(vb[3]);
    }

    // Scores: accS over kc, sh then sl per kc (same order as staged version)
    float4v accS = {};
    for (int kc = 0; kc < 4; ++kc) {
        short8_t sh = *(const short8_t*)&Sgh[mrow * 128 + kc * 32 + quad * 8];
        short8_t sl = *(const short8_t*)&Sgl[mrow * 128 + kc * 32 + quad * 8];
        accS = __builtin_amdgcn_mfma_f32_16x16x32_bf16(ah[kc], sh, accS, 0, 0, 0);
        accS = __builtin_amdgcn_mfma_f32_16x16x32_bf16(ah[kc], sl, accS, 0, 0, 0);
    }
    for (int r = 0; r < 4; ++r) {
        int nrow = nbase + quad * 4 + r;
        if (nrow < nnodes) {
            if (mrow < 4) s_src[nrow * 4 + mrow] = accS[r];
            else if (mrow < 8) s_tgt[nrow * 4 + (mrow - 4)] = accS[r];
        }
    }

    // Main GEMM: hb halves sequential (acc reused -> VGPR <= 64)
    for (int hb = 0; hb < 2; ++hb) {
        float4v acc[4] = {};
        for (int kc = 0; kc < 4; ++kc) {
#pragma unroll
            for (int t = 0; t < 4; ++t) {
                short8_t bh = *(const short8_t*)&Wb[(size_t)(hb * 64 + t * 16 + mrow) * 128 +
                                                    kc * 32 + quad * 8];
                acc[t] = __builtin_amdgcn_mfma_f32_16x16x32_bf16(ah[kc], bh, acc[t], 0, 0, 0);
            }
        }
        for (int t = 0; t < 4; ++t)
            for (int r = 0; r < 4; ++r) {
                int nrow = nbase + quad * 4 + r;
                if (nrow < nnodes)
                    Hwb[(size_t)nrow * 128 + hb * 64 + t * 16 + mrow] = f2bf(acc[t][r]);
            }
    }
}

// ---------------- S1: single-pass scatter with atomic window reservation
// (round-11/14, unchanged).
__global__ __launch_bounds__(256) void k_scatA(const int* __restrict__ raw,
                                               int* __restrict__ cnt,
                                               unsigned int* __restrict__ pairs,
                                               int E, int N, int NB) {
    __shared__ unsigned int pl[CHUNK];
    __shared__ unsigned short bl[CHUNK];
    __shared__ int h[512];
    __shared__ int s_i64;
    const int tid = threadIdx.x;
    for (int i = tid; i < 512; i += 256) h[i] = 0;
    if (tid < 64) {
        unsigned int hiw = ((const unsigned int*)raw)[2 * tid + 1];
        unsigned long long b = __ballot(hiw == 0u);
        if (tid == 0) s_i64 = (__popcll(b) >= 32) ? 1 : 0;
    }
    __syncthreads();
    const bool i64 = s_i64 != 0;
    const int eBeg = blockIdx.x * CHUNK;
    const int eEnd = min(E, eBeg + CHUNK);
    const int cntE = eEnd - eBeg;
    for (int j = tid; j < cntE; j += 256) {
        int i = eBeg + j;
        int s, t;
        if (i64) {
            s = raw[2 * (size_t)i];
            t = raw[2 * ((size_t)E + i)];
        } else {
            s = raw[(size_t)i];
            t = raw[(size_t)E + i];
        }
        s = s < 0 ? 0 : (s >= N ? N - 1 : s);
        t = t < 0 ? 0 : (t >= N ? N - 1 : t);
        pl[j] = (unsigned)s | ((unsigned)(t & 255) << 24);
        int b = t >> 8;
        bl[j] = (unsigned short)b;
        atomicAdd(&h[b], 1);
    }
    __syncthreads();
    for (int b = tid; b < NB; b += 256) {
        int c = h[b];
        if (c > 0) h[b] = b * CAP + atomicAdd(&cnt[b], c);
    }
    __syncthreads();
    for (int j = tid; j < cntE; j += 256) {
        int slot = atomicAdd(&h[bl[j]], 1);
        pairs[slot] = pl[j];
    }
}

// ---------------- k_locs: per-bucket local CSR build + inline base scan
// (round-14, unchanged).
__global__ __launch_bounds__(256) void k_locs(const unsigned int* __restrict__ pairs,
                                              const int* __restrict__ cnt,
                                              int* __restrict__ offs,
                                              int* __restrict__ csr, int N, int NB,
                                              int E) {
    __shared__ int dcnt[256], cur[256];
    __shared__ int rsum[4];
    const int b = blockIdx.x;
    const int tid = threadIdx.x;

    int part = 0;
    for (int j = tid; j < b; j += 256) part += cnt[j];
    for (int d = 1; d < 64; d <<= 1) part += __shfl_xor(part, d, 64);
    if ((tid & 63) == 0) rsum[tid >> 6] = part;
    __syncthreads();
    const int obase = rsum[0] + rsum[1] + rsum[2] + rsum[3];

    const int c = cnt[b];
    const int rbeg = b * CAP;
    const int nodeBase = b << 8;
    dcnt[tid] = 0;
    __syncthreads();
    for (int i = tid; i < c; i += 256) atomicAdd(&dcnt[pairs[rbeg + i] >> 24], 1);
    __syncthreads();
    int v = dcnt[tid];
    int e = block_excl_scan(v);
    int n = nodeBase + tid;
    if (n < N) offs[n] = obase + e;
    cur[tid] = obase + e;
    __syncthreads();
    for (int i = tid; i < c; i += 256) {
        unsigned p = pairs[rbeg + i];
        int slot = atomicAdd(&cur[p >> 24], 1);
        csr[slot] = (int)(p & 0x00FFFFFFu);
    }
    if (b == 0 && tid == 0) offs[N] = E;
}

// ---------------- K5: per-node softmax + aggregation + ELU (round-8/9/11/14,
// unchanged: 8-deep + 4-deep + scalar gather tails).
__global__ __launch_bounds__(256) void k_aggr(const int* __restrict__ offs,
                                              const int* __restrict__ csr,
                                              const float* __restrict__ s_src,
                                              const float* __restrict__ s_tgt,
                                              const unsigned int* __restrict__ Hwb,
                                              float* __restrict__ out, int nnodes) {
    __shared__ int srcs[4][64];
    __shared__ __align__(16) float wbuf[4][64 * 4];
    int wave = threadIdx.x >> 6, lane = threadIdx.x & 63;
    int n = blockIdx.x * 4 + wave;
    if (n >= nnodes) return;
    int off = offs[n];
    int deg = offs[n + 1] - off;
    int h = lane >> 4;

    const float4v* ss4 = (const float4v*)s_src;
    float4v st = ((const float4v*)s_tgt)[n];

    float se0 = 0.f, se1 = 0.f, se2 = 0.f, se3 = 0.f;
    float acc0 = 0.f, acc1 = 0.f;

    for (int base = 0; base < deg; base += 64) {
        int cnt = min(64, deg - base);
        asm volatile("s_waitcnt lgkmcnt(0)" ::: "memory");
        if (lane < cnt) {
            int s = csr[off + base + lane];
            srcs[wave][lane] = s;
            float4v ss = ss4[s];
            float4v w;
            for (int c = 0; c < 4; ++c) {
                float x = ss[c] + st[c];
                x = fminf(fmaxf(x, 0.2f * x), 60.f);
                w[c] = __expf(x);
            }
            se0 += w[0]; se1 += w[1]; se2 += w[2]; se3 += w[3];
            *(float4v*)&wbuf[wave][lane * 4] = w;
        }
        asm volatile("s_waitcnt lgkmcnt(0)" ::: "memory");

        int k = 0;
        for (; k + 8 <= cnt; k += 8) {
            int q0 = srcs[wave][k], q1 = srcs[wave][k + 1];
            int q2 = srcs[wave][k + 2], q3 = srcs[wave][k + 3];
            int q4 = srcs[wave][k + 4], q5 = srcs[wave][k + 5];
            int q6 = srcs[wave][k + 6], q7 = srcs[wave][k + 7];
            float w0 = wbuf[wave][k * 4 + h], w1 = wbuf[wave][(k + 1) * 4 + h];
            float w2 = wbuf[wave][(k + 2) * 4 + h], w3 = wbuf[wave][(k + 3) * 4 + h];
            float w4 = wbuf[wave][(k + 4) * 4 + h], w5 = wbuf[wave][(k + 5) * 4 + h];
            float w6 = wbuf[wave][(k + 6) * 4 + h], w7 = wbuf[wave][(k + 7) * 4 + h];
            unsigned int u0 = Hwb[(size_t)q0 * 64 + lane];
            unsigned int u1 = Hwb[(size_t)q1 * 64 + lane];
            unsigned int u2 = Hwb[(size_t)q2 * 64 + lane];
            unsigned int u3 = Hwb[(size_t)q3 * 64 + lane];
            unsigned int u4 = Hwb[(size_t)q4 * 64 + lane];
            unsigned int u5 = Hwb[(size_t)q5 * 64 + lane];
            unsigned int u6 = Hwb[(size_t)q6 * 64 + lane];
            unsigned int u7 = Hwb[(size_t)q7 * 64 + lane];
            acc0 += w0 * __uint_as_float(u0 << 16);
            acc1 += w0 * __uint_as_float(u0 & 0xffff0000u);
            acc0 += w1 * __uint_as_float(u1 << 16);
            acc1 += w1 * __uint_as_float(u1 & 0xffff0000u);
            acc0 += w2 * __uint_as_float(u2 << 16);
            acc1 += w2 * __uint_as_float(u2 & 0xffff0000u);
            acc0 += w3 * __uint_as_float(u3 << 16);
            acc1 += w3 * __uint_as_float(u3 & 0xffff0000u);
            acc0 += w4 * __uint_as_float(u4 << 16);
            acc1 += w4 * __uint_as_float(u4 & 0xffff0000u);
            acc0 += w5 * __uint_as_float(u5 << 16);
            acc1 += w5 * __uint_as_float(u5 & 0xffff0000u);
            acc0 += w6 * __uint_as_float(u6 << 16);
            acc1 += w6 * __uint_as_float(u6 & 0xffff0000u);
            acc0 += w7 * __uint_as_float(u7 << 16);
            acc1 += w7 * __uint_as_float(u7 & 0xffff0000u);
        }
        for (; k + 4 <= cnt; k += 4) {
            int q0 = srcs[wave][k], q1 = srcs[wave][k + 1];
            int q2 = srcs[wave][k + 2], q3 = srcs[wave][k + 3];
            float w0 = wbuf[wave][k * 4 + h], w1 = wbuf[wave][(k + 1) * 4 + h];
            float w2 = wbuf[wave][(k + 2) * 4 + h], w3 = wbuf[wave][(k + 3) * 4 + h];
            unsigned int u0 = Hwb[(size_t)q0 * 64 + lane];
            unsigned int u1 = Hwb[(size_t)q1 * 64 + lane];
            unsigned int u2 = Hwb[(size_t)q2 * 64 + lane];
            unsigned int u3 = Hwb[(size_t)q3 * 64 + lane];
            acc0 += w0 * __uint_as_float(u0 << 16);
            acc1 += w0 * __uint_as_float(u0 & 0xffff0000u);
            acc0 += w1 * __uint_as_float(u1 << 16);
            acc1 += w1 * __uint_as_float(u1 & 0xffff0000u);
            acc0 += w2 * __uint_as_float(u2 << 16);
            acc1 += w2 * __uint_as_float(u2 & 0xffff0000u);
            acc0 += w3 * __uint_as_float(u3 << 16);
            acc1 += w3 * __uint_as_float(u3 & 0xffff0000u);
        }
        for (; k < cnt; ++k) {
            int q = srcs[wave][k];
            float w = wbuf[wave][k * 4 + h];
            unsigned int u = Hwb[(size_t)q * 64 + lane];
            acc0 += w * __uint_as_float(u << 16);
            acc1 += w * __uint_as_float(u & 0xffff0000u);
        }
    }

    for (int d = 1; d < 64; d <<= 1) {
        se0 += __shfl_xor(se0, d, 64);
        se1 += __shfl_xor(se1, d, 64);
        se2 += __shfl_xor(se2, d, 64);
        se3 += __shfl_xor(se3, d, 64);
    }
    float seh = (h == 0) ? se0 : (h == 1) ? se1 : (h == 2) ? se2 : se3;
    float inv = seh > 0.f ? 1.0f / seh : 0.f;
    acc0 *= inv;
    acc1 *= inv;
    acc0 = acc0 > 0.f ? acc0 : __expf(acc0) - 1.0f;
    acc1 = acc1 > 0.f ? acc1 : __expf(acc1) - 1.0f;

    int o = (2 * lane) & 31;
    float2v val = {acc0, acc1};
    *(float2v*)&out[(((size_t)h * nnodes + n) * 32) + o] = val;
}

extern "C" void kernel_launch(void* const* d_in, const int* in_sizes, int n_in,
                              void* d_out, int out_size, void* d_ws, size_t ws_size,
                              hipStream_t stream) {
    const float* Hin = (const float*)d_in[0];
    const int* ei_raw = (const int*)d_in[1];
    const float* W = (const float*)d_in[2];
    const float* Asrc = (const float*)d_in[3];
    const float* Atgt = (const float*)d_in[4];
    int N = in_sizes[0] / 128;
    int E = in_sizes[1] / 2;
    int NB = (N + 255) >> 8;             // node buckets (256 nodes each)
    int nblkE = (E + CHUNK - 1) / CHUNK; // edge chunks

    char* ws = (char*)d_ws;
    size_t p = 0;
    auto alloc = [&](size_t bytes) {
        void* r = ws + p;
        p = (p + bytes + 511) & ~(size_t)511;
        return r;
    };
    unsigned short* Hwb = (unsigned short*)alloc((size_t)N * 128 * 2);  // 25.6 MB
    float* s_src = (float*)alloc((size_t)N * 4 * 4);
    float* s_tgt = (float*)alloc((size_t)N * 4 * 4);
    int* offs = (int*)alloc((size_t)(N + 1) * 4);
    int* csr = (int*)alloc((size_t)E * 4);
    unsigned int* pairs = (unsigned int*)alloc((size_t)NB * CAP * 4);  // 12.8 MB
    int* cnt = (int*)alloc((size_t)NB * 4);
    unsigned short* Wb = (unsigned short*)alloc(128 * 128 * 2);   // 32 KB
    unsigned short* Sgh = (unsigned short*)alloc(16 * 128 * 2);   // 4 KB
    unsigned short* Sgl = (unsigned short*)alloc(16 * 128 * 2);   // 4 KB

    k_wprep<<<dim3(1), 256, 0, stream>>>(W, Asrc, Atgt, Wb, Sgh, Sgl, cnt, NB);
    k_hw2<<<dim3((N + 127) / 128), 512, 0, stream>>>(Hin, Wb, Sgh, Sgl, Hwb, s_src,
                                                     s_tgt, N);
    k_scatA<<<dim3(nblkE), 256, 0, stream>>>(ei_raw, cnt, pairs, E, N, NB);
    k_locs<<<dim3(NB), 256, 0, stream>>>(pairs, cnt, offs, csr, N, NB, E);

    k_aggr<<<dim3((N + 3) / 4), 256, 0, stream>>>(offs, csr, s_src, s_tgt,
                                                  (const unsigned int*)Hwb,
                                                  (float*)d_out, N);
}

// Round 12
// 245.746 us; speedup vs baseline: 1.5900x; 1.5900x over previous
//
#include <hip/hip_runtime.h>

// GAT layer: N=100000 nodes, E=1600000 edges, 4 heads, D_in=128, D_out=32.
// Dtypes (settled): floats f32 (bf16-valued: lo-split == 0 bitwise), edge_index
// int64 (ballot-detected), output f32. Hw stored bf16.
// Round-18: CONSOLIDATION of proven-passing parts only.
//  - r17's barrier-free k_hw2 was bit-exact but 216us (global B-operand gather
//    storm: MfmaUtil 0.7%, ~40 latency-bound loads/wave, no reuse). REVERTED.
//  - k_hw: r15's exact passing body (staged LDS, 782 blocks, nh loop, cnt[]
//    zeroed by block 0 -> replaces memset dispatch). 47us measured, passing.
//  - k_scatA / k_locs / k_aggr: r14's exact passing bodies (248.1us build).
//  - History: k_hw structural edits failed 3x unexplained (r12/r13/r16) and
//    the LDS-free replacement regressed 4.6x (r17). k_hw is frozen.
// Pipeline: k_hw(+cnt zero) -> k_scatA -> k_locs -> k_aggr  (4 dispatches).

#define CHUNK 4096
#define CAP 8192

typedef __attribute__((ext_vector_type(8))) short short8_t;
typedef __attribute__((ext_vector_type(4))) float float4v;
typedef __attribute__((ext_vector_type(2))) float float2v;

static __device__ inline float bf2f(unsigned short u) {
    return __uint_as_float(((unsigned int)u) << 16);
}
static __device__ inline unsigned short f2bf(float f) {
    unsigned int u = __float_as_uint(f);
    return (unsigned short)((u + 0x7fffu + ((u >> 16) & 1u)) >> 16);
}
static __device__ inline void splitf(float v, unsigned short& h, unsigned short& l) {
    unsigned short hb = f2bf(v);
    h = hb;
    l = f2bf(v - bf2f(hb));  // residual exact in f32
}

// ---------------- 256-thread block exclusive scan helper
__device__ inline int block_excl_scan(int v) {
    __shared__ int wsum[8];
    int lane = threadIdx.x & 63, w = threadIdx.x >> 6;
    int inc = v;
    for (int d = 1; d < 64; d <<= 1) {
        int t = __shfl_up(inc, d, 64);
        if (lane >= d) inc += t;
    }
    if (lane == 63) wsum[w] = inc;
    __syncthreads();
    int base = 0;
    for (int i = 0; i < w; ++i) base += wsum[i];
    __syncthreads();
    return base + inc - v;
}

// ---------------- S1: single-pass scatter with atomic window reservation
// (round-11/14, unchanged).
__global__ __launch_bounds__(256) void k_scatA(const int* __restrict__ raw,
                                               int* __restrict__ cnt,
                                               unsigned int* __restrict__ pairs,
                                               int E, int N, int NB) {
    __shared__ unsigned int pl[CHUNK];
    __shared__ unsigned short bl[CHUNK];
    __shared__ int h[512];
    __shared__ int s_i64;
    const int tid = threadIdx.x;
    for (int i = tid; i < 512; i += 256) h[i] = 0;
    if (tid < 64) {
        unsigned int hiw = ((const unsigned int*)raw)[2 * tid + 1];
        unsigned long long b = __ballot(hiw == 0u);
        if (tid == 0) s_i64 = (__popcll(b) >= 32) ? 1 : 0;
    }
    __syncthreads();
    const bool i64 = s_i64 != 0;
    const int eBeg = blockIdx.x * CHUNK;
    const int eEnd = min(E, eBeg + CHUNK);
    const int cntE = eEnd - eBeg;
    for (int j = tid; j < cntE; j += 256) {
        int i = eBeg + j;
        int s, t;
        if (i64) {
            s = raw[2 * (size_t)i];
            t = raw[2 * ((size_t)E + i)];
        } else {
            s = raw[(size_t)i];
            t = raw[(size_t)E + i];
        }
        s = s < 0 ? 0 : (s >= N ? N - 1 : s);
        t = t < 0 ? 0 : (t >= N ? N - 1 : t);
        pl[j] = (unsigned)s | ((unsigned)(t & 255) << 24);
        int b = t >> 8;
        bl[j] = (unsigned short)b;
        atomicAdd(&h[b], 1);
    }
    __syncthreads();
    for (int b = tid; b < NB; b += 256) {
        int c = h[b];
        if (c > 0) h[b] = b * CAP + atomicAdd(&cnt[b], c);
    }
    __syncthreads();
    for (int j = tid; j < cntE; j += 256) {
        int slot = atomicAdd(&h[bl[j]], 1);
        pairs[slot] = pl[j];
    }
}

// ---------------- k_locs: per-bucket local CSR build + inline base scan
// (round-14, unchanged).
__global__ __launch_bounds__(256) void k_locs(const unsigned int* __restrict__ pairs,
                                              const int* __restrict__ cnt,
                                              int* __restrict__ offs,
                                              int* __restrict__ csr, int N, int NB,
                                              int E) {
    __shared__ int dcnt[256], cur[256];
    __shared__ int rsum[4];
    const int b = blockIdx.x;
    const int tid = threadIdx.x;

    int part = 0;
    for (int j = tid; j < b; j += 256) part += cnt[j];
    for (int d = 1; d < 64; d <<= 1) part += __shfl_xor(part, d, 64);
    if ((tid & 63) == 0) rsum[tid >> 6] = part;
    __syncthreads();
    const int obase = rsum[0] + rsum[1] + rsum[2] + rsum[3];

    const int c = cnt[b];
    const int rbeg = b * CAP;
    const int nodeBase = b << 8;
    dcnt[tid] = 0;
    __syncthreads();
    for (int i = tid; i < c; i += 256) atomicAdd(&dcnt[pairs[rbeg + i] >> 24], 1);
    __syncthreads();
    int v = dcnt[tid];
    int e = block_excl_scan(v);
    int n = nodeBase + tid;
    if (n < N) offs[n] = obase + e;
    cur[tid] = obase + e;
    __syncthreads();
    for (int i = tid; i < c; i += 256) {
        unsigned p = pairs[rbeg + i];
        int slot = atomicAdd(&cur[p >> 24], 1);
        csr[slot] = (int)(p & 0x00FFFFFFu);
    }
    if (b == 0 && tid == 0) offs[N] = E;
}

// ---------------- K1: fused GEMM + scores (round-15's exact passing body:
// staged LDS, 782 blocks x 128 nodes, nh loop; block 0 zeroes cnt[]).
__global__ __launch_bounds__(256) void k_hw(const float* __restrict__ Hf,
                                            const float* __restrict__ Wf,
                                            const float* __restrict__ Asrc,
                                            const float* __restrict__ Atgt,
                                            unsigned short* __restrict__ Hwb,
                                            float* __restrict__ s_src,
                                            float* __restrict__ s_tgt, int nnodes,
                                            int* __restrict__ cnt, int NB) {
    __shared__ __align__(16) unsigned short Wh[64 * 136];
    __shared__ __align__(16) unsigned short Sh[16 * 136];
    __shared__ __align__(16) unsigned short Sl[16 * 136];
    __shared__ float sAs[128], sAt[128];

    if (blockIdx.x == 0) {
        for (int i = threadIdx.x; i < NB; i += 256) cnt[i] = 0;
    }

    int wave = threadIdx.x >> 6;
    int lane = threadIdx.x & 63;
    int mrow = lane & 15;
    int quad = lane >> 4;

    if (threadIdx.x < 128) {
        sAs[threadIdx.x] = Asrc[threadIdx.x];
        sAt[threadIdx.x] = Atgt[threadIdx.x];
    }
    __syncthreads();

    for (int i = threadIdx.x; i < 512; i += 256) {
        int r = i >> 5, c4 = (i & 31) * 4;
        float4v v = {0.f, 0.f, 0.f, 0.f};
        if (r < 8) {
            int hh_ = r & 3;
            const float* Ap = (r < 4) ? sAs : sAt;
            for (int o = 0; o < 32; ++o) {
                float4v w4 = *(const float4v*)(Wf + ((size_t)(hh_ * 32 + o)) * 128 + c4);
                float a = Ap[hh_ * 32 + o];
                v[0] += w4[0] * a;
                v[1] += w4[1] * a;
                v[2] += w4[2] * a;
                v[3] += w4[3] * a;
            }
        }
        ushort4 h4, l4;
        unsigned short hh, ll;
        splitf(v[0], hh, ll); h4.x = hh; l4.x = ll;
        splitf(v[1], hh, ll); h4.y = hh; l4.y = ll;
        splitf(v[2], hh, ll); h4.z = hh; l4.z = ll;
        splitf(v[3], hh, ll); h4.w = hh; l4.w = ll;
        *(ushort4*)&Sh[r * 136 + c4] = h4;
        *(ushort4*)&Sl[r * 136 + c4] = l4;
    }

    const float4v* wsrc = (const float4v*)Wf;

    for (int hb = 0; hb < 2; ++hb) {
        if (hb) __syncthreads();
        for (int i = threadIdx.x; i < 2048; i += 256) {
            int r = i >> 5, c4 = (i & 31) * 4;
            float4v v = wsrc[(hb * 64 + r) * 32 + (i & 31)];
            ushort4 h4;
            h4.x = f2bf(v[0]);
            h4.y = f2bf(v[1]);
            h4.z = f2bf(v[2]);
            h4.w = f2bf(v[3]);
            *(ushort4*)&Wh[r * 136 + c4] = h4;
        }
        __syncthreads();

        for (int nh = 0; nh < 2; ++nh) {
            int nbase = blockIdx.x * 128 + (wave * 2 + nh) * 16;
            if (nbase >= nnodes) continue;
            int anode = nbase + mrow;
            int nclamp = anode < nnodes ? anode : nnodes - 1;
            const float* Hp = Hf + (size_t)nclamp * 128 + quad * 8;

            float4v acc[4] = {};
            float4v accS = {};
            for (int kc = 0; kc < 4; ++kc) {
                float4v va = *(const float4v*)(Hp + kc * 32);
                float4v vb = *(const float4v*)(Hp + kc * 32 + 4);
                short8_t ah;
                ah[0] = (short)f2bf(va[0]);
                ah[1] = (short)f2bf(va[1]);
                ah[2] = (short)f2bf(va[2]);
                ah[3] = (short)f2bf(va[3]);
                ah[4] = (short)f2bf(vb[0]);
                ah[5] = (short)f2bf(vb[1]);
                ah[6] = (short)f2bf(vb[2]);
                ah[7] = (short)f2bf(vb[3]);
                for (int t = 0; t < 4; ++t) {
                    int boff = (t * 16 + mrow) * 136 + kc * 32 + quad * 8;
                    short8_t bh = *(const short8_t*)&Wh[boff];
                    acc[t] = __builtin_amdgcn_mfma_f32_16x16x32_bf16(ah, bh, acc[t], 0, 0, 0);
                }
                if (hb == 0) {
                    int soff = mrow * 136 + kc * 32 + quad * 8;
                    short8_t sh = *(const short8_t*)&Sh[soff];
                    short8_t sl = *(const short8_t*)&Sl[soff];
                    accS = __builtin_amdgcn_mfma_f32_16x16x32_bf16(ah, sh, accS, 0, 0, 0);
                    accS = __builtin_amdgcn_mfma_f32_16x16x32_bf16(ah, sl, accS, 0, 0, 0);
                }
            }
            for (int t = 0; t < 4; ++t)
                for (int r = 0; r < 4; ++r) {
                    int nrow = nbase + quad * 4 + r;
                    if (nrow < nnodes)
                        Hwb[(size_t)nrow * 128 + hb * 64 + t * 16 + mrow] = f2bf(acc[t][r]);
                }
            if (hb == 0) {
                for (int r = 0; r < 4; ++r) {
                    int nrow = nbase + quad * 4 + r;
                    if (nrow < nnodes) {
                        if (mrow < 4) s_src[nrow * 4 + mrow] = accS[r];
                        else if (mrow < 8) s_tgt[nrow * 4 + (mrow - 4)] = accS[r];
                    }
                }
            }
        }
    }
}

// ---------------- K5: per-node softmax + aggregation + ELU (round-8/9/11/14,
// unchanged: 8-deep + 4-deep + scalar gather tails).
__global__ __launch_bounds__(256) void k_aggr(const int* __restrict__ offs,
                                              const int* __restrict__ csr,
                                              const float* __restrict__ s_src,
                                              const float* __restrict__ s_tgt,
                                              const unsigned int* __restrict__ Hwb,
                                              float* __restrict__ out, int nnodes) {
    __shared__ int srcs[4][64];
    __shared__ __align__(16) float wbuf[4][64 * 4];
    int wave = threadIdx.x >> 6, lane = threadIdx.x & 63;
    int n = blockIdx.x * 4 + wave;
    if (n >= nnodes) return;
    int off = offs[n];
    int deg = offs[n + 1] - off;
    int h = lane >> 4;

    const float4v* ss4 = (const float4v*)s_src;
    float4v st = ((const float4v*)s_tgt)[n];

    float se0 = 0.f, se1 = 0.f, se2 = 0.f, se3 = 0.f;
    float acc0 = 0.f, acc1 = 0.f;

    for (int base = 0; base < deg; base += 64) {
        int cnt = min(64, deg - base);
        asm volatile("s_waitcnt lgkmcnt(0)" ::: "memory");
        if (lane < cnt) {
            int s = csr[off + base + lane];
            srcs[wave][lane] = s;
            float4v ss = ss4[s];
            float4v w;
            for (int c = 0; c < 4; ++c) {
                float x = ss[c] + st[c];
                x = fminf(fmaxf(x, 0.2f * x), 60.f);
                w[c] = __expf(x);
            }
            se0 += w[0]; se1 += w[1]; se2 += w[2]; se3 += w[3];
            *(float4v*)&wbuf[wave][lane * 4] = w;
        }
        asm volatile("s_waitcnt lgkmcnt(0)" ::: "memory");

        int k = 0;
        for (; k + 8 <= cnt; k += 8) {
            int q0 = srcs[wave][k], q1 = srcs[wave][k + 1];
            int q2 = srcs[wave][k + 2], q3 = srcs[wave][k + 3];
            int q4 = srcs[wave][k + 4], q5 = srcs[wave][k + 5];
            int q6 = srcs[wave][k + 6], q7 = srcs[wave][k + 7];
            float w0 = wbuf[wave][k * 4 + h], w1 = wbuf[wave][(k + 1) * 4 + h];
            float w2 = wbuf[wave][(k + 2) * 4 + h], w3 = wbuf[wave][(k + 3) * 4 + h];
            float w4 = wbuf[wave][(k + 4) * 4 + h], w5 = wbuf[wave][(k + 5) * 4 + h];
            float w6 = wbuf[wave][(k + 6) * 4 + h], w7 = wbuf[wave][(k + 7) * 4 + h];
            unsigned int u0 = Hwb[(size_t)q0 * 64 + lane];
            unsigned int u1 = Hwb[(size_t)q1 * 64 + lane];
            unsigned int u2 = Hwb[(size_t)q2 * 64 + lane];
            unsigned int u3 = Hwb[(size_t)q3 * 64 + lane];
            unsigned int u4 = Hwb[(size_t)q4 * 64 + lane];
            unsigned int u5 = Hwb[(size_t)q5 * 64 + lane];
            unsigned int u6 = Hwb[(size_t)q6 * 64 + lane];
            unsigned int u7 = Hwb[(size_t)q7 * 64 + lane];
            acc0 += w0 * __uint_as_float(u0 << 16);
            acc1 += w0 * __uint_as_float(u0 & 0xffff0000u);
            acc0 += w1 * __uint_as_float(u1 << 16);
            acc1 += w1 * __uint_as_float(u1 & 0xffff0000u);
            acc0 += w2 * __uint_as_float(u2 << 16);
            acc1 += w2 * __uint_as_float(u2 & 0xffff0000u);
            acc0 += w3 * __uint_as_float(u3 << 16);
            acc1 += w3 * __uint_as_float(u3 & 0xffff0000u);
            acc0 += w4 * __uint_as_float(u4 << 16);
            acc1 += w4 * __uint_as_float(u4 & 0xffff0000u);
            acc0 += w5 * __uint_as_float(u5 << 16);
            acc1 += w5 * __uint_as_float(u5 & 0xffff0000u);
            acc0 += w6 * __uint_as_float(u6 << 16);
            acc1 += w6 * __uint_as_float(u6 & 0xffff0000u);
            acc0 += w7 * __uint_as_float(u7 << 16);
            acc1 += w7 * __uint_as_float(u7 & 0xffff0000u);
        }
        for (; k + 4 <= cnt; k += 4) {
            int q0 = srcs[wave][k], q1 = srcs[wave][k + 1];
            int q2 = srcs[wave][k + 2], q3 = srcs[wave][k + 3];
            float w0 = wbuf[wave][k * 4 + h], w1 = wbuf[wave][(k + 1) * 4 + h];
            float w2 = wbuf[wave][(k + 2) * 4 + h], w3 = wbuf[wave][(k + 3) * 4 + h];
            unsigned int u0 = Hwb[(size_t)q0 * 64 + lane];
            unsigned int u1 = Hwb[(size_t)q1 * 64 + lane];
            unsigned int u2 = Hwb[(size_t)q2 * 64 + lane];
            unsigned int u3 = Hwb[(size_t)q3 * 64 + lane];
            acc0 += w0 * __uint_as_float(u0 << 16);
            acc1 += w0 * __uint_as_float(u0 & 0xffff0000u);
            acc0 += w1 * __uint_as_float(u1 << 16);
            acc1 += w1 * __uint_as_float(u1 & 0xffff0000u);
            acc0 += w2 * __uint_as_float(u2 << 16);
            acc1 += w2 * __uint_as_float(u2 & 0xffff0000u);
            acc0 += w3 * __uint_as_float(u3 << 16);
            acc1 += w3 * __uint_as_float(u3 & 0xffff0000u);
        }
        for (; k < cnt; ++k) {
            int q = srcs[wave][k];
            float w = wbuf[wave][k * 4 + h];
            unsigned int u = Hwb[(size_t)q * 64 + lane];
            acc0 += w * __uint_as_float(u << 16);
            acc1 += w * __uint_as_float(u & 0xffff0000u);
        }
    }

    for (int d = 1; d < 64; d <<= 1) {
        se0 += __shfl_xor(se0, d, 64);
        se1 += __shfl_xor(se1, d, 64);
        se2 += __shfl_xor(se2, d, 64);
        se3 += __shfl_xor(se3, d, 64);
    }
    float seh = (h == 0) ? se0 : (h == 1) ? se1 : (h == 2) ? se2 : se3;
    float inv = seh > 0.f ? 1.0f / seh : 0.f;
    acc0 *= inv;
    acc1 *= inv;
    acc0 = acc0 > 0.f ? acc0 : __expf(acc0) - 1.0f;
    acc1 = acc1 > 0.f ? acc1 : __expf(acc1) - 1.0f;

    int o = (2 * lane) & 31;
    float2v val = {acc0, acc1};
    *(float2v*)&out[(((size_t)h * nnodes + n) * 32) + o] = val;
}

extern "C" void kernel_launch(void* const* d_in, const int* in_sizes, int n_in,
                              void* d_out, int out_size, void* d_ws, size_t ws_size,
                              hipStream_t stream) {
    const float* Hin = (const float*)d_in[0];
    const int* ei_raw = (const int*)d_in[1];
    const float* W = (const float*)d_in[2];
    const float* Asrc = (const float*)d_in[3];
    const float* Atgt = (const float*)d_in[4];
    int N = in_sizes[0] / 128;
    int E = in_sizes[1] / 2;
    int NB = (N + 255) >> 8;             // node buckets (256 nodes each)
    int nblkE = (E + CHUNK - 1) / CHUNK; // edge chunks

    char* ws = (char*)d_ws;
    size_t p = 0;
    auto alloc = [&](size_t bytes) {
        void* r = ws + p;
        p = (p + bytes + 511) & ~(size_t)511;
        return r;
    };
    unsigned short* Hwb = (unsigned short*)alloc((size_t)N * 128 * 2);  // 25.6 MB
    float* s_src = (float*)alloc((size_t)N * 4 * 4);
    float* s_tgt = (float*)alloc((size_t)N * 4 * 4);
    int* offs = (int*)alloc((size_t)(N + 1) * 4);
    int* csr = (int*)alloc((size_t)E * 4);
    unsigned int* pairs = (unsigned int*)alloc((size_t)NB * CAP * 4);  // 12.8 MB
    int* cnt = (int*)alloc((size_t)NB * 4);

    k_hw<<<dim3((N + 127) / 128), 256, 0, stream>>>(Hin, W, Asrc, Atgt, Hwb, s_src,
                                                    s_tgt, N, cnt, NB);
    k_scatA<<<dim3(nblkE), 256, 0, stream>>>(ei_raw, cnt, pairs, E, N, NB);
    k_locs<<<dim3(NB), 256, 0, stream>>>(pairs, cnt, offs, csr, N, NB, E);

    k_aggr<<<dim3((N + 3) / 4), 256, 0, stream>>>(offs, csr, s_src, s_tgt,
                                                  (const unsigned int*)Hwb,
                                                  (float*)d_out, N);
}